// Round 4
// baseline (395.178 us; speedup 1.0000x reference)
//
#include <hip/hip_runtime.h>
#include <stdint.h>

// ============================================================================
// AttentionBlock: out = concat([x, softmax(QK^T/32) @ V], -1)
//   B=4, S=2048, D=1024, fp32 in/out.
//
// fp32 emulated via f16 hi/lo split on the Q/K/logits path, folded into the
// K dimension: A''=[Ah|Al|Ah], B''=[Bh|Bh|Bl], K=3072 -> plain f16 GEMMs
// with a per-K-region source table.
//
// ONE 256x256 template (BK=64, 8 waves 2Mx4N, 128KiB LDS, dbuf), now with
// TWO phases per K-tile and fragment carry-over (minimal LDS reads:
// 24 ds_read_b128 per wave per K-tile = each byte read once per wave):
//   Phase A: stage u0,u1,u2(kt+1) -> dsread A-half0(8) + B-all(8) -> bar ->
//            lgkmcnt(0) -> 32 MFMA -> vmcnt(6) -> bar   [publishes u3(kt)]
//   Phase B: stage u3(kt+1) -> dsread A-half1(8) -> bar -> lgkmcnt(0) ->
//            32 MFMA -> vmcnt(2) -> bar                 [publishes u0-2(kt+1)]
// In-flight ledger (2 loads/unit/wave): prologue 8 -> vmcnt(2); steady
// A: 6+2 -> vmcnt(6); B: 2+6 -> vmcnt(2); peel vmcnt(0) once. Every unit
// has a uniform 2-phase publish lead; never drains to 0 in main loop (T4).
// T1: bijective XCD swizzle (all grids have nwg % 8 == 0).
//
// ws layout (144 MiB):
//    0 MB Qh | 16 Ql | 32 Kh | 48 Kl | 64 VT f16 [4][1024][2048]
//   80 MB S f32 [4][2048][2048] (P f16 written in-place, row stride 8192B)
//   overlay on S (dead before S written): 80 xh | 96 xl | 112.. W*T hi/lo
// ============================================================================

typedef _Float16 h8 __attribute__((ext_vector_type(8)));
typedef _Float16 h4 __attribute__((ext_vector_type(4)));
typedef float    f4 __attribute__((ext_vector_type(4)));

#define VMCNT(n) asm volatile("s_waitcnt vmcnt(" #n ")" ::: "memory")
#define BAR() __builtin_amdgcn_s_barrier()
#define LGKM0_FENCE()                                      \
  asm volatile("s_waitcnt lgkmcnt(0)" ::: "memory");       \
  __builtin_amdgcn_sched_barrier(0)

__device__ __forceinline__ void gl_lds16(const _Float16* g, _Float16* l) {
  __builtin_amdgcn_global_load_lds(
      (const __attribute__((address_space(1))) unsigned int*)g,
      (__attribute__((address_space(3))) unsigned int*)l, 16, 0, 0);
}

// ---------------------------------------------------------------- prep ----
__global__ __launch_bounds__(256) void prep_x_split_copy(
    const float* __restrict__ x, _Float16* __restrict__ xh,
    _Float16* __restrict__ xl, float* __restrict__ out) {
  size_t i = (size_t)blockIdx.x * 256 + threadIdx.x;  // one f4 per thread
  f4 v = ((const f4*)x)[i];
  h4 hi, lo;
#pragma unroll
  for (int j = 0; j < 4; ++j) {
    _Float16 h = (_Float16)v[j];
    hi[j] = h;
    lo[j] = (_Float16)(v[j] - (float)h);
  }
  ((h4*)xh)[i] = hi;
  ((h4*)xl)[i] = lo;
  size_t r = i >> 8, c = i & 255;       // out[:, :1024] = x (fused copy)
  ((f4*)out)[r * 512 + c] = v;
}

__global__ __launch_bounds__(256) void prep_w_split(const float* __restrict__ W,
                                                    _Float16* __restrict__ WTh,
                                                    _Float16* __restrict__ WTl) {
  int i = blockIdx.x * 256 + threadIdx.x;
  int d = i >> 10, e = i & 1023;
  float v = W[i];
  _Float16 h = (_Float16)v;
  WTh[e * 1024 + d] = h;
  if (WTl) WTl[e * 1024 + d] = (_Float16)(v - (float)h);
}

// ---------------------------------------------------------------- gemm ----
enum { EM_F32 = 0, EM_QK = 1, EM_VT = 2 };

struct G8 {
  const _Float16* Areg[3]; long zA; int lda;     // A region table (k0>>10)
  const _Float16* Breg[4][3]; long zB; int ldb;  // B region table per z
  int NT[4];     // K-tiles (K/64) per z
  int emode[4];  // epilogue per z
  float* Cf; long zC; int ldc; float scale;      // EM_F32
  _Float16* Ch[4]; _Float16* Cl[4];              // EM_QK (ld = 1024)
  _Float16* Vt;                                  // EM_VT: [b][1024][2048]
};

__global__ __launch_bounds__(512) void gemm8p(G8 p) {
  __shared__ alignas(16) _Float16 lds[2][2][256][64];  // [buf][A/B][row][col]
  const int t = threadIdx.x;
  const int lane = t & 63;
  const int w = t >> 6;
  const int wm = w >> 2, wn = w & 3;           // wave grid 2(M) x 4(N)
  const int l15 = lane & 15, l4 = lane >> 4;

  // T1: bijective XCD-aware block swizzle (nwg % 8 == 0 for all launches)
  const int nbx = gridDim.x, nby = gridDim.y;
  const int nwg = nbx * nby * gridDim.z;
  const int bid = blockIdx.x + nbx * (blockIdx.y + nby * blockIdx.z);
  const int nb = (bid & 7) * (nwg >> 3) + (bid >> 3);
  const int bx = nb % nbx, by = (nb / nbx) % nby, z = nb / (nbx * nby);

  const long Mb = (long)by * 256;
  const long Nb = (long)bx * 256;
  const int nt = p.NT[z];
  const long zAo = p.zA * z;
  const long zBo = p.zB * z;
  const int lda = p.lda, ldb = p.ldb;

  const int rr_lo = t >> 3;            // staging: 8 lanes per 64-f16 row
  const int slot = t & 7;
  const int rr0_lo = (t & ~63) >> 3;   // wave-uniform row part

  f4 acc[8][4] = {};                   // wave tile 128x64: frag[i<8][j<4]

  // stage unit u (0:A qm=0, 1:B qn-half0, 2:B qn-half1, 3:A qm=1) -> buf sb
  auto stage = [&](int u, int sb, int kt) {
    const int k0 = kt << 6;
    const int r = k0 >> 10;
    const int cn = k0 & 1023;
    const _Float16* Ab = p.Areg[r] + zAo + cn;
    const _Float16* Bb = p.Breg[z][r] + zBo + cn;
#pragma unroll
    for (int i = 0; i < 2; ++i) {
      int rr = i * 64 + rr_lo;
      int rr0 = i * 64 + rr0_lo;
      if (u == 0 || u == 3) {
        int qm = (u == 3);
        int row  = ((rr  >> 6) << 7) | (qm << 6) | (rr  & 63);
        int row0 = ((rr0 >> 6) << 7) | (qm << 6) | (rr0 & 63);
        int scol = (slot ^ (row & 7)) << 3;     // pre-swizzled source (T2)
        gl_lds16(Ab + (Mb + row) * (long)lda + scol, &lds[sb][0][row0][0]);
      } else {
        int qn = (u == 2);
        int row  = ((rr  >> 5) << 6) | (qn << 5) | (rr  & 31);
        int row0 = ((rr0 >> 5) << 6) | (qn << 5) | (rr0 & 31);
        int scol = (slot ^ (row & 7)) << 3;
        gl_lds16(Bb + (Nb + row) * (long)ldb + scol, &lds[sb][1][row0][0]);
      }
    }
  };

  h8 af[4][2], bf[4][2];

  auto dsA = [&](int qm, int buf) {   // 8x ds_read_b128
#pragma unroll
    for (int m = 0; m < 4; ++m) {
      int row = wm * 128 + qm * 64 + m * 16 + l15;
#pragma unroll
      for (int ks = 0; ks < 2; ++ks)
        af[m][ks] = *(const h8*)&lds[buf][0][row][(((ks * 4 + l4) ^ (row & 7)) << 3)];
    }
  };
  auto dsB = [&](int buf) {           // 8x ds_read_b128 (all 4 n-frags)
#pragma unroll
    for (int n = 0; n < 4; ++n) {
      int row = wn * 64 + n * 16 + l15;
#pragma unroll
      for (int ks = 0; ks < 2; ++ks)
        bf[n][ks] = *(const h8*)&lds[buf][1][row][(((ks * 4 + l4) ^ (row & 7)) << 3)];
    }
  };
  auto mfma32 = [&](int qm) {         // one M-half x full N x K=64
    __builtin_amdgcn_s_setprio(1);
#pragma unroll
    for (int ks = 0; ks < 2; ++ks)
#pragma unroll
      for (int m = 0; m < 4; ++m)
#pragma unroll
        for (int n = 0; n < 4; ++n)
          acc[qm * 4 + m][n] = __builtin_amdgcn_mfma_f32_16x16x32_f16(
              af[m][ks], bf[n][ks], acc[qm * 4 + m][n], 0, 0, 0);
    __builtin_amdgcn_s_setprio(0);
  };

  // prologue: stage tile 0, publish u0,u1,u2 (u3 stays in flight)
  stage(0, 0, 0); stage(1, 0, 0); stage(2, 0, 0); stage(3, 0, 0);
  VMCNT(2);
  BAR();

  for (int kt = 0; kt < nt - 1; ++kt) {
    const int buf = kt & 1;
    // ---- phase A ----
    stage(0, buf ^ 1, kt + 1); stage(1, buf ^ 1, kt + 1); stage(2, buf ^ 1, kt + 1);
    dsA(0, buf); dsB(buf);
    BAR();
    LGKM0_FENCE();
    mfma32(0);
    VMCNT(6); BAR();                 // publishes u3(kt)
    // ---- phase B ----
    stage(3, buf ^ 1, kt + 1);
    dsA(1, buf);
    BAR();
    LGKM0_FENCE();
    mfma32(1);
    VMCNT(2); BAR();                 // publishes u0,u1,u2(kt+1)
  }
  {  // last tile: no staging
    const int buf = (nt - 1) & 1;
    dsA(0, buf); dsB(buf);
    BAR();
    LGKM0_FENCE();
    mfma32(0);
    VMCNT(0); BAR();                 // publishes u3(last)
    dsA(1, buf);
    BAR();
    LGKM0_FENCE();
    mfma32(1);                       // epilogue is LDS-free
  }

  // epilogue: C/D map col=lane&15, row=(lane>>4)*4+reg (verified rounds 1/3)
  const int em = p.emode[z];
  const long gr0 = wm * 128 + l4 * 4;
  const long gc0 = wn * 64 + l15;
  if (em == EM_F32) {
    float* C = p.Cf + p.zC * z;
#pragma unroll
    for (int i = 0; i < 8; ++i)
#pragma unroll
      for (int j = 0; j < 4; ++j) {
        long gr = Mb + gr0 + i * 16;
        long gc = Nb + gc0 + j * 16;
#pragma unroll
        for (int r = 0; r < 4; ++r)
          C[(gr + r) * (long)p.ldc + gc] = acc[i][j][r] * p.scale;
      }
  } else if (em == EM_QK) {
    _Float16* Ch = p.Ch[z];
    _Float16* Cl = p.Cl[z];
#pragma unroll
    for (int i = 0; i < 8; ++i)
#pragma unroll
      for (int j = 0; j < 4; ++j) {
        long gr = Mb + gr0 + i * 16;
        long gc = Nb + gc0 + j * 16;
#pragma unroll
        for (int r = 0; r < 4; ++r) {
          float c = acc[i][j][r];
          _Float16 h = (_Float16)c;
          Ch[(gr + r) * 1024 + gc] = h;
          Cl[(gr + r) * 1024 + gc] = (_Float16)(c - (float)h);
        }
      }
  } else {  // EM_VT: rows = b*2048+s, col = d -> Vt[b][d][s], 4 contiguous s
    _Float16* Vt = p.Vt;
#pragma unroll
    for (int i = 0; i < 8; ++i)
#pragma unroll
      for (int j = 0; j < 4; ++j) {
        long gr = Mb + gr0 + i * 16;
        long gc = Nb + gc0 + j * 16;
        long b = gr >> 11, s = gr & 2047;
        h4 hv;
#pragma unroll
        for (int r = 0; r < 4; ++r) hv[r] = (_Float16)acc[i][j][r];
        *(h4*)&Vt[b * (long)(1024 * 2048) + gc * 2048 + s] = hv;
      }
  }
}

// ------------------------------------------------------------- softmax ----
__global__ __launch_bounds__(256) void softmax_rows(float* __restrict__ Sb) {
  const int t = threadIdx.x;
  float* row = Sb + (size_t)blockIdx.x * 2048;
  f4 v0 = ((const f4*)row)[t];
  f4 v1 = ((const f4*)row)[t + 256];
  float mx = -3.0e38f;
#pragma unroll
  for (int j = 0; j < 4; ++j) { mx = fmaxf(mx, v0[j]); mx = fmaxf(mx, v1[j]); }
#pragma unroll
  for (int o = 32; o > 0; o >>= 1) mx = fmaxf(mx, __shfl_xor(mx, o));
  __shared__ float red[4], red2[4];
  const int wave = t >> 6, lane = t & 63;
  if (lane == 0) red[wave] = mx;
  __syncthreads();
  mx = fmaxf(fmaxf(red[0], red[1]), fmaxf(red[2], red[3]));
  float pv[8];
  float sum = 0.f;
#pragma unroll
  for (int j = 0; j < 4; ++j) { pv[j] = __expf(v0[j] - mx); pv[4 + j] = __expf(v1[j] - mx); }
#pragma unroll
  for (int j = 0; j < 8; ++j) sum += pv[j];
#pragma unroll
  for (int o = 32; o > 0; o >>= 1) sum += __shfl_xor(sum, o);
  if (lane == 0) red2[wave] = sum;
  __syncthreads();  // orders all row reads before in-place f16 writes
  sum = red2[0] + red2[1] + red2[2] + red2[3];
  float inv = 1.0f / sum;
  h4 o0, o1;
#pragma unroll
  for (int j = 0; j < 4; ++j) { o0[j] = (_Float16)(pv[j] * inv); o1[j] = (_Float16)(pv[4 + j] * inv); }
  _Float16* prow = (_Float16*)row;
  ((h4*)prow)[t] = o0;
  ((h4*)prow)[t + 256] = o1;
}

// ---------------------------------------------------------------- misc ----
__global__ __launch_bounds__(256) void copy_x_half(const float* __restrict__ x,
                                                   float* __restrict__ out) {
  size_t i = (size_t)blockIdx.x * 256 + threadIdx.x;
  size_t r = i >> 8, c = i & 255;
  ((f4*)out)[r * 512 + c] = ((const f4*)x)[i];
}

__global__ void ws_sentinel(float* out, float v) { out[0] = v; }

// -------------------------------------------------------------- launch ----
extern "C" void kernel_launch(void* const* d_in, const int* in_sizes, int n_in,
                              void* d_out, int out_size, void* d_ws, size_t ws_size,
                              hipStream_t stream) {
  const float* x  = (const float*)d_in[0];
  const float* Wq = (const float*)d_in[1];
  const float* Wk = (const float*)d_in[2];
  const float* Wv = (const float*)d_in[3];
  float* out = (float*)d_out;

  const size_t MB = 1ull << 20;
  char* w = (char*)d_ws;
  _Float16* Qh = (_Float16*)(w + 0 * MB);
  _Float16* Ql = (_Float16*)(w + 16 * MB);
  _Float16* Kh = (_Float16*)(w + 32 * MB);
  _Float16* Kl = (_Float16*)(w + 48 * MB);
  _Float16* VT = (_Float16*)(w + 64 * MB);
  float*    S  = (float*)   (w + 80 * MB);
  _Float16* xh = (_Float16*)(w + 80 * MB);  // overlays S (dead before S write)
  _Float16* xl = (_Float16*)(w + 96 * MB);
  _Float16* WqhT = (_Float16*)(w + 112 * MB);
  _Float16* WqlT = (_Float16*)(w + 114 * MB);
  _Float16* WkhT = (_Float16*)(w + 116 * MB);
  _Float16* WklT = (_Float16*)(w + 118 * MB);
  _Float16* WvhT = (_Float16*)(w + 120 * MB);

  if (ws_size < 144 * MB) {  // fail loud: absmax reports ~ws_size
    copy_x_half<<<8192, 256, 0, stream>>>(x, out);
    ws_sentinel<<<1, 1, 0, stream>>>(out, (float)ws_size);
    return;
  }

  prep_x_split_copy<<<8192, 256, 0, stream>>>(x, xh, xl, out);
  prep_w_split<<<4096, 256, 0, stream>>>(Wq, WqhT, WqlT);
  prep_w_split<<<4096, 256, 0, stream>>>(Wk, WkhT, WklT);
  prep_w_split<<<4096, 256, 0, stream>>>(Wv, WvhT, (_Float16*)nullptr);

  // --- Q,K (split, K=3072) + V (plain, K=1024) in one 384-block launch ---
  G8 pp = {};
  pp.Areg[0] = xh; pp.Areg[1] = xl; pp.Areg[2] = xh; pp.zA = 0; pp.lda = 1024;
  pp.Breg[0][0] = WqhT; pp.Breg[0][1] = WqhT; pp.Breg[0][2] = WqlT;
  pp.Breg[1][0] = WkhT; pp.Breg[1][1] = WkhT; pp.Breg[1][2] = WklT;
  pp.Breg[2][0] = WvhT; pp.Breg[2][1] = WvhT; pp.Breg[2][2] = WvhT;
  pp.zB = 0; pp.ldb = 1024;
  pp.NT[0] = 48; pp.NT[1] = 48; pp.NT[2] = 16;
  pp.emode[0] = EM_QK; pp.emode[1] = EM_QK; pp.emode[2] = EM_VT;
  pp.Ch[0] = Qh; pp.Cl[0] = Ql; pp.Ch[1] = Kh; pp.Cl[1] = Kl;
  pp.Vt = VT;
  gemm8p<<<dim3(4, 32, 3), 512, 0, stream>>>(pp);

  // --- S = (Q K^T)/32, split K=3072, 256 blocks ---
  G8 ps = {};
  ps.Areg[0] = Qh; ps.Areg[1] = Ql; ps.Areg[2] = Qh;
  ps.zA = 2048L * 1024; ps.lda = 1024;
  for (int zz = 0; zz < 4; ++zz) {
    ps.Breg[zz][0] = Kh; ps.Breg[zz][1] = Kh; ps.Breg[zz][2] = Kl;
    ps.NT[zz] = 48; ps.emode[zz] = EM_F32;
  }
  ps.zB = 2048L * 1024; ps.ldb = 1024;
  ps.Cf = S; ps.zC = 2048L * 2048; ps.ldc = 2048; ps.scale = 0.03125f;
  gemm8p<<<dim3(8, 8, 4), 512, 0, stream>>>(ps);

  softmax_rows<<<8192, 256, 0, stream>>>(S);

  // --- attn = P @ V -> out[:, :, 1024:], plain K=2048, 128 blocks ---
  G8 po = {};
  const _Float16* P = (const _Float16*)S;  // rows stride 4096 f16
  po.Areg[0] = P; po.Areg[1] = P + 1024; po.Areg[2] = P;
  po.zA = 2048L * 4096; po.lda = 4096;
  for (int zz = 0; zz < 4; ++zz) {
    po.Breg[zz][0] = VT; po.Breg[zz][1] = VT + 1024; po.Breg[zz][2] = VT;
    po.NT[zz] = 32; po.emode[zz] = EM_F32;
  }
  po.zB = 1024L * 2048; po.ldb = 2048;
  po.Cf = out + 1024; po.zC = 2048L * 2048; po.ldc = 2048; po.scale = 1.f;
  gemm8p<<<dim3(4, 8, 4), 512, 0, stream>>>(po);
}

// Round 5
// 394.667 us; speedup vs baseline: 1.0013x; 1.0013x over previous
//
#include <hip/hip_runtime.h>
#include <stdint.h>

// ============================================================================
// AttentionBlock: out = concat([x, softmax(QK^T/32) @ V], -1)
//   B=4, S=2048, D=1024, fp32 in/out.
//
// fp32 emulated via f16 hi/lo split on the Q/K/logits path, folded into the
// K dimension: A''=[Ah|Al|Ah], B''=[Bh|Bh|Bl], K=3072 -> plain f16 GEMMs
// with a per-K-region source table.
//
// GEMM template (256xBN tile, BK=64, 8 waves 2Mx4N, dbuf LDS, gload_lds +
// T2 pre-swizzled source, T1 XCD swizzle): FOUR phases per K-tile with
// fragment REUSE (Gray order) — 24 ds_read_b128/wave/tile (r3 had 48 = LDS
// bound; r4 had 24 but 1-phase staging lead = latency bound):
//   P0: read A-quad0(8)+B-half0(4); stage B0(t+1); BAR; lgkm0; MFMA A0xB0
//   P1: read B-half1(4);            stage B1(t+1); BAR; lgkm0; MFMA A0xB1
//   P2: read A-quad1(8);            stage A1(t+1); BAR; lgkm0; MFMA A1xB1
//   P3: (no reads);                 stage A0(t+2); BAR;        MFMA A1xB0
// In-flight ledger (BN=256, 2 loads/unit/thread), publishes before the
// end-of-phase barrier:
//   t.P0-end: queue B1(t),A1(t),A0(t+1),B0(t+1)=8 -> vmcnt(6) publ B1(t)
//   t.P1-end: queue A1(t),A0(t+1),B0,B1=8        -> vmcnt(6) publ A1(t)
//   t.P2-end: none
//   t.P3-end: queue A0,B0,B1,A1(t+1),A0(t+2)=10  -> vmcnt(6) publ A0,B0(t+1)
// Leads: 3-4 phases (~1200+ cyc > 900 HBM). Never below 6 in steady (T4).
// Tail: t=nt-2 skips A0-stage (P3-end vmcnt(4)); t=nt-1 stages nothing
// (waits 2,0,-,-). A0(t+2) writes the CURRENT read-buf's A0 region — safe:
// its reads completed at t.P0 (3 barriers earlier); regions A0/A1 disjoint.
// BN=128 (PV: N=1024 -> 256 blocks, full machine): B-halves are 1 load each;
// ledger gives PRO=5, W0=5, W1=4, W3=5, tail 4/2/0.
//
// ws layout (144 MiB):
//    0 MB Qh | 16 Ql | 32 Kh | 48 Kl | 64 VT f16 [4][1024][2048]
//   80 MB S f32 [4][2048][2048] (P f16 written in-place, row stride 8192B)
//   overlay on S (dead before S written): 80 xh | 96 xl | 112.. W*T hi/lo
// ============================================================================

typedef _Float16 h8 __attribute__((ext_vector_type(8)));
typedef _Float16 h4 __attribute__((ext_vector_type(4)));
typedef float    f4 __attribute__((ext_vector_type(4)));

#define BAR() __builtin_amdgcn_s_barrier()
#define LGKM0_FENCE()                                      \
  asm volatile("s_waitcnt lgkmcnt(0)" ::: "memory");       \
  __builtin_amdgcn_sched_barrier(0)

template <int N>
__device__ __forceinline__ void vmw() {
  if constexpr (N == 0) asm volatile("s_waitcnt vmcnt(0)" ::: "memory");
  else if constexpr (N == 2) asm volatile("s_waitcnt vmcnt(2)" ::: "memory");
  else if constexpr (N == 3) asm volatile("s_waitcnt vmcnt(3)" ::: "memory");
  else if constexpr (N == 4) asm volatile("s_waitcnt vmcnt(4)" ::: "memory");
  else if constexpr (N == 5) asm volatile("s_waitcnt vmcnt(5)" ::: "memory");
  else if constexpr (N == 6) asm volatile("s_waitcnt vmcnt(6)" ::: "memory");
}

__device__ __forceinline__ void gl_lds16(const _Float16* g, _Float16* l) {
  __builtin_amdgcn_global_load_lds(
      (const __attribute__((address_space(1))) unsigned int*)g,
      (__attribute__((address_space(3))) unsigned int*)l, 16, 0, 0);
}

// ---------------------------------------------------------------- prep ----
__global__ __launch_bounds__(256) void prep_x_split_copy(
    const float* __restrict__ x, _Float16* __restrict__ xh,
    _Float16* __restrict__ xl, float* __restrict__ out) {
  size_t i = (size_t)blockIdx.x * 256 + threadIdx.x;  // one f4 per thread
  f4 v = ((const f4*)x)[i];
  h4 hi, lo;
#pragma unroll
  for (int j = 0; j < 4; ++j) {
    _Float16 h = (_Float16)v[j];
    hi[j] = h;
    lo[j] = (_Float16)(v[j] - (float)h);
  }
  ((h4*)xh)[i] = hi;
  ((h4*)xl)[i] = lo;
  size_t r = i >> 8, c = i & 255;       // out[:, :1024] = x (fused copy)
  ((f4*)out)[r * 512 + c] = v;
}

__global__ __launch_bounds__(256) void prep_w_split(const float* __restrict__ W,
                                                    _Float16* __restrict__ WTh,
                                                    _Float16* __restrict__ WTl) {
  int i = blockIdx.x * 256 + threadIdx.x;
  int d = i >> 10, e = i & 1023;
  float v = W[i];
  _Float16 h = (_Float16)v;
  WTh[e * 1024 + d] = h;
  if (WTl) WTl[e * 1024 + d] = (_Float16)(v - (float)h);
}

// ---------------------------------------------------------------- gemm ----
enum { EM_F32 = 0, EM_QK = 1, EM_VT = 2 };

struct G8 {
  const _Float16* Areg[3]; long zA; int lda;     // A region table (k0>>10)
  const _Float16* Breg[4][3]; long zB; int ldb;  // B region table per z
  int NT[4];     // K-tiles (K/64) per z
  int emode[4];  // epilogue per z
  float* Cf; long zC; int ldc; float scale;      // EM_F32
  _Float16* Ch[4]; _Float16* Cl[4];              // EM_QK (ld = 1024)
  _Float16* Vt;                                  // EM_VT: [b][1024][2048]
};

template <int BN>
__global__ __launch_bounds__(512, 2) void gemmdp(G8 p) {
  constexpr int NFR = BN / 64;   // n-frags per wave (4 or 2)
  constexpr int NPH = NFR / 2;   // n-frags per B-half (2 or 1)
  __shared__ alignas(16) _Float16 ldsA[2][256][64];
  __shared__ alignas(16) _Float16 ldsB[2][BN][64];

  const int t0 = threadIdx.x;
  const int lane = t0 & 63;
  const int w = t0 >> 6;
  const int wm = w >> 2, wn = w & 3;           // wave grid 2(M) x 4(N)
  const int l15 = lane & 15, l4 = lane >> 4;

  // T1: bijective XCD-aware block swizzle (nwg % 8 == 0 for all launches)
  const int nbx = gridDim.x, nby = gridDim.y;
  const int nwg = nbx * nby * gridDim.z;
  const int bid = blockIdx.x + nbx * (blockIdx.y + nby * blockIdx.z);
  const int nb = (bid & 7) * (nwg >> 3) + (bid >> 3);
  const int bx = nb % nbx, by = (nb / nbx) % nby, z = nb / (nbx * nby);

  const long Mb = (long)by * 256;
  const long Nb = (long)bx * BN;
  const int nt = p.NT[z];
  const long zAo = p.zA * z;
  const long zBo = p.zB * z;
  const int lda = p.lda, ldb = p.ldb;

  const int rr_lo = t0 >> 3;            // staging: 8 lanes per 64-f16 row
  const int slot = t0 & 7;
  const int rr0_lo = (t0 & ~63) >> 3;   // wave-uniform row part

  f4 acc[8][NFR] = {};                  // wave tile 128 x (16*NFR)

  // stage unit u (0:A-half0, 1:B-half0, 2:B-half1, 3:A-half1) of kt -> buf sb
  auto stage = [&](int u, int sb, int kt) {
    const int k0 = kt << 6;
    const int r = k0 >> 10;
    const int cn = k0 & 1023;
    if (u == 0 || u == 3) {
      const _Float16* Ab = p.Areg[r] + zAo + cn;
      int qm = (u == 3);
#pragma unroll
      for (int i = 0; i < 2; ++i) {
        int rr = i * 64 + rr_lo;
        int rr0 = i * 64 + rr0_lo;
        int row  = ((rr  >> 6) << 7) | (qm << 6) | (rr  & 63);
        int row0 = ((rr0 >> 6) << 7) | (qm << 6) | (rr0 & 63);
        int scol = (slot ^ (row & 7)) << 3;     // pre-swizzled source (T2)
        gl_lds16(Ab + (Mb + row) * (long)lda + scol, &ldsA[sb][row0][0]);
      }
    } else {
      const _Float16* Bb = p.Breg[z][r] + zBo + cn;
      int h = (u == 2);
      if constexpr (BN == 256) {
#pragma unroll
        for (int i = 0; i < 2; ++i) {
          int rr = i * 64 + rr_lo;
          int rr0 = i * 64 + rr0_lo;
          int row  = ((rr  >> 5) << 6) | (h << 5) | (rr  & 31);
          int row0 = ((rr0 >> 5) << 6) | (h << 5) | (rr0 & 31);
          int scol = (slot ^ (row & 7)) << 3;
          gl_lds16(Bb + (Nb + row) * (long)ldb + scol, &ldsB[sb][row0][0]);
        }
      } else {  // BN=128: 1 load/thread (64 rows)
        int rr = rr_lo, rr0 = rr0_lo;
        int row  = ((rr  >> 4) << 5) | (h << 4) | (rr  & 15);
        int row0 = ((rr0 >> 4) << 5) | (h << 4) | (rr0 & 15);
        int scol = (slot ^ (row & 7)) << 3;
        gl_lds16(Bb + (Nb + row) * (long)ldb + scol, &ldsB[sb][row0][0]);
      }
    }
  };

  h8 af[4][2];          // current A-quad (reused across 2 phases)
  h8 bfh[2][NPH][2];    // both B-halves (B0 live P0->P3)

  auto dsA = [&](int qm, int buf) {   // 8x ds_read_b128
#pragma unroll
    for (int m = 0; m < 4; ++m) {
      int row = wm * 128 + (qm * 4 + m) * 16 + l15;
#pragma unroll
      for (int ks = 0; ks < 2; ++ks)
        af[m][ks] = *(const h8*)&ldsA[buf][row][(((ks * 4 + l4) ^ (row & 7)) << 3)];
    }
  };
  auto dsB = [&](int h, int buf) {    // NPH*2 ds_read_b128
#pragma unroll
    for (int n = 0; n < NPH; ++n) {
      int row = wn * (16 * NFR) + (h * NPH + n) * 16 + l15;
#pragma unroll
      for (int ks = 0; ks < 2; ++ks)
        bfh[h][n][ks] = *(const h8*)&ldsB[buf][row][(((ks * 4 + l4) ^ (row & 7)) << 3)];
    }
  };
  auto mfma16 = [&](int qm, int h) {  // A-quad x B-half x K=64
    __builtin_amdgcn_s_setprio(1);
#pragma unroll
    for (int ks = 0; ks < 2; ++ks)
#pragma unroll
      for (int m = 0; m < 4; ++m)
#pragma unroll
        for (int n = 0; n < NPH; ++n)
          acc[qm * 4 + m][h * NPH + n] = __builtin_amdgcn_mfma_f32_16x16x32_f16(
              af[m][ks], bfh[h][n][ks], acc[qm * 4 + m][h * NPH + n], 0, 0, 0);
    __builtin_amdgcn_s_setprio(0);
  };

  // ledger constants (loads per unit: BN=256: all 2; BN=128: A=2, B=1)
  constexpr int PRO = (BN == 256) ? 6 : 5;
  constexpr int W0  = (BN == 256) ? 6 : 5;
  constexpr int W1  = (BN == 256) ? 6 : 4;
  constexpr int W3  = (BN == 256) ? 6 : 5;
  constexpr int W3b = 4;   // nt-2.P3-end (no A0-stage)
  constexpr int W0c = 2;   // nt-1.P0-end

  // prologue: A0(0),B0(0),B1(0),A1(0) -> buf0; A0(1) -> buf1
  stage(0, 0, 0); stage(1, 0, 0); stage(2, 0, 0); stage(3, 0, 0);
  stage(0, 1, 1);
  vmw<PRO>();
  BAR();

  int kt = 0;
  for (; kt + 2 < nt; ++kt) {
    const int buf = kt & 1;
    // P0
    dsA(0, buf); dsB(0, buf);
    stage(1, buf ^ 1, kt + 1);
    BAR(); LGKM0_FENCE();
    mfma16(0, 0);
    vmw<W0>(); BAR();
    // P1
    dsB(1, buf);
    stage(2, buf ^ 1, kt + 1);
    BAR(); LGKM0_FENCE();
    mfma16(0, 1);
    vmw<W1>(); BAR();
    // P2
    dsA(1, buf);
    stage(3, buf ^ 1, kt + 1);
    BAR(); LGKM0_FENCE();
    mfma16(1, 1);
    BAR();
    // P3 (no reads; A0(kt+2) goes into the CURRENT buf — region read at P0)
    stage(0, buf, kt + 2);
    BAR();
    mfma16(1, 0);
    vmw<W3>(); BAR();
  }
  {  // kt = nt-2: stage B0,B1,A1(nt-1) only
    const int buf = kt & 1;
    dsA(0, buf); dsB(0, buf);
    stage(1, buf ^ 1, kt + 1);
    BAR(); LGKM0_FENCE();
    mfma16(0, 0);
    vmw<W0>(); BAR();
    dsB(1, buf);
    stage(2, buf ^ 1, kt + 1);
    BAR(); LGKM0_FENCE();
    mfma16(0, 1);
    vmw<W1>(); BAR();
    dsA(1, buf);
    stage(3, buf ^ 1, kt + 1);
    BAR(); LGKM0_FENCE();
    mfma16(1, 1);
    BAR();
    mfma16(1, 0);
    vmw<W3b>(); BAR();
    ++kt;
  }
  {  // kt = nt-1: no staging; drain
    const int buf = kt & 1;
    dsA(0, buf); dsB(0, buf);
    BAR(); LGKM0_FENCE();
    mfma16(0, 0);
    vmw<W0c>(); BAR();
    dsB(1, buf);
    BAR(); LGKM0_FENCE();
    mfma16(0, 1);
    vmw<0>(); BAR();
    dsA(1, buf);
    BAR(); LGKM0_FENCE();
    mfma16(1, 1);
    mfma16(1, 0);          // epilogue is LDS-free; no trailing barrier
  }

  // epilogue: C/D map col=lane&15, row=(lane>>4)*4+reg (verified r1/r3)
  const int em = p.emode[z];
  const long gr0 = wm * 128 + l4 * 4;
  const long gc0 = wn * (16 * NFR) + l15;
  if (em == EM_F32) {
    float* C = p.Cf + p.zC * z;
#pragma unroll
    for (int i = 0; i < 8; ++i)
#pragma unroll
      for (int j = 0; j < NFR; ++j) {
        long gr = Mb + gr0 + i * 16;
        long gc = Nb + gc0 + j * 16;
#pragma unroll
        for (int r = 0; r < 4; ++r)
          C[(gr + r) * (long)p.ldc + gc] = acc[i][j][r] * p.scale;
      }
  } else if (em == EM_QK) {
    _Float16* Ch = p.Ch[z];
    _Float16* Cl = p.Cl[z];
#pragma unroll
    for (int i = 0; i < 8; ++i)
#pragma unroll
      for (int j = 0; j < NFR; ++j) {
        long gr = Mb + gr0 + i * 16;
        long gc = Nb + gc0 + j * 16;
#pragma unroll
        for (int r = 0; r < 4; ++r) {
          float c = acc[i][j][r];
          _Float16 h = (_Float16)c;
          Ch[(gr + r) * 1024 + gc] = h;
          Cl[(gr + r) * 1024 + gc] = (_Float16)(c - (float)h);
        }
      }
  } else {  // EM_VT: rows = b*2048+s, col = d -> Vt[b][d][s], 4 contiguous s
    _Float16* Vt = p.Vt;
#pragma unroll
    for (int i = 0; i < 8; ++i)
#pragma unroll
      for (int j = 0; j < NFR; ++j) {
        long gr = Mb + gr0 + i * 16;
        long gc = Nb + gc0 + j * 16;
        long b = gr >> 11, s = gr & 2047;
        h4 hv;
#pragma unroll
        for (int r = 0; r < 4; ++r) hv[r] = (_Float16)acc[i][j][r];
        *(h4*)&Vt[b * (long)(1024 * 2048) + gc * 2048 + s] = hv;
      }
  }
}

// ------------------------------------------------------------- softmax ----
__global__ __launch_bounds__(256) void softmax_rows(float* __restrict__ Sb) {
  const int t = threadIdx.x;
  float* row = Sb + (size_t)blockIdx.x * 2048;
  f4 v0 = ((const f4*)row)[t];
  f4 v1 = ((const f4*)row)[t + 256];
  float mx = -3.0e38f;
#pragma unroll
  for (int j = 0; j < 4; ++j) { mx = fmaxf(mx, v0[j]); mx = fmaxf(mx, v1[j]); }
#pragma unroll
  for (int o = 32; o > 0; o >>= 1) mx = fmaxf(mx, __shfl_xor(mx, o));
  __shared__ float red[4], red2[4];
  const int wave = t >> 6, lane = t & 63;
  if (lane == 0) red[wave] = mx;
  __syncthreads();
  mx = fmaxf(fmaxf(red[0], red[1]), fmaxf(red[2], red[3]));
  float pv[8];
  float sum = 0.f;
#pragma unroll
  for (int j = 0; j < 4; ++j) { pv[j] = __expf(v0[j] - mx); pv[4 + j] = __expf(v1[j] - mx); }
#pragma unroll
  for (int j = 0; j < 8; ++j) sum += pv[j];
#pragma unroll
  for (int o = 32; o > 0; o >>= 1) sum += __shfl_xor(sum, o);
  if (lane == 0) red2[wave] = sum;
  __syncthreads();  // orders all row reads before in-place f16 writes
  sum = red2[0] + red2[1] + red2[2] + red2[3];
  float inv = 1.0f / sum;
  h4 o0, o1;
#pragma unroll
  for (int j = 0; j < 4; ++j) { o0[j] = (_Float16)(pv[j] * inv); o1[j] = (_Float16)(pv[4 + j] * inv); }
  _Float16* prow = (_Float16*)row;
  ((h4*)prow)[t] = o0;
  ((h4*)prow)[t + 256] = o1;
}

// ---------------------------------------------------------------- misc ----
__global__ __launch_bounds__(256) void copy_x_half(const float* __restrict__ x,
                                                   float* __restrict__ out) {
  size_t i = (size_t)blockIdx.x * 256 + threadIdx.x;
  size_t r = i >> 8, c = i & 255;
  ((f4*)out)[r * 512 + c] = ((const f4*)x)[i];
}

__global__ void ws_sentinel(float* out, float v) { out[0] = v; }

// -------------------------------------------------------------- launch ----
extern "C" void kernel_launch(void* const* d_in, const int* in_sizes, int n_in,
                              void* d_out, int out_size, void* d_ws, size_t ws_size,
                              hipStream_t stream) {
  const float* x  = (const float*)d_in[0];
  const float* Wq = (const float*)d_in[1];
  const float* Wk = (const float*)d_in[2];
  const float* Wv = (const float*)d_in[3];
  float* out = (float*)d_out;

  const size_t MB = 1ull << 20;
  char* w = (char*)d_ws;
  _Float16* Qh = (_Float16*)(w + 0 * MB);
  _Float16* Ql = (_Float16*)(w + 16 * MB);
  _Float16* Kh = (_Float16*)(w + 32 * MB);
  _Float16* Kl = (_Float16*)(w + 48 * MB);
  _Float16* VT = (_Float16*)(w + 64 * MB);
  float*    S  = (float*)   (w + 80 * MB);
  _Float16* xh = (_Float16*)(w + 80 * MB);  // overlays S (dead before S write)
  _Float16* xl = (_Float16*)(w + 96 * MB);
  _Float16* WqhT = (_Float16*)(w + 112 * MB);
  _Float16* WqlT = (_Float16*)(w + 114 * MB);
  _Float16* WkhT = (_Float16*)(w + 116 * MB);
  _Float16* WklT = (_Float16*)(w + 118 * MB);
  _Float16* WvhT = (_Float16*)(w + 120 * MB);

  if (ws_size < 144 * MB) {  // fail loud: absmax reports ~ws_size
    copy_x_half<<<8192, 256, 0, stream>>>(x, out);
    ws_sentinel<<<1, 1, 0, stream>>>(out, (float)ws_size);
    return;
  }

  prep_x_split_copy<<<8192, 256, 0, stream>>>(x, xh, xl, out);
  prep_w_split<<<4096, 256, 0, stream>>>(Wq, WqhT, WqlT);
  prep_w_split<<<4096, 256, 0, stream>>>(Wk, WkhT, WklT);
  prep_w_split<<<4096, 256, 0, stream>>>(Wv, WvhT, (_Float16*)nullptr);

  // --- Q,K (split, K=3072) + V (plain, K=1024) in one 384-block launch ---
  G8 pp = {};
  pp.Areg[0] = xh; pp.Areg[1] = xl; pp.Areg[2] = xh; pp.zA = 0; pp.lda = 1024;
  pp.Breg[0][0] = WqhT; pp.Breg[0][1] = WqhT; pp.Breg[0][2] = WqlT;
  pp.Breg[1][0] = WkhT; pp.Breg[1][1] = WkhT; pp.Breg[1][2] = WklT;
  pp.Breg[2][0] = WvhT; pp.Breg[2][1] = WvhT; pp.Breg[2][2] = WvhT;
  pp.zB = 0; pp.ldb = 1024;
  pp.NT[0] = 48; pp.NT[1] = 48; pp.NT[2] = 16;
  pp.emode[0] = EM_QK; pp.emode[1] = EM_QK; pp.emode[2] = EM_VT;
  pp.Ch[0] = Qh; pp.Cl[0] = Ql; pp.Ch[1] = Kh; pp.Cl[1] = Kl;
  pp.Vt = VT;
  gemmdp<256><<<dim3(4, 32, 3), 512, 0, stream>>>(pp);

  // --- S = (Q K^T)/32, split K=3072, 256 blocks ---
  G8 ps = {};
  ps.Areg[0] = Qh; ps.Areg[1] = Ql; ps.Areg[2] = Qh;
  ps.zA = 2048L * 1024; ps.lda = 1024;
  for (int zz = 0; zz < 4; ++zz) {
    ps.Breg[zz][0] = Kh; ps.Breg[zz][1] = Kh; ps.Breg[zz][2] = Kl;
    ps.NT[zz] = 48; ps.emode[zz] = EM_F32;
  }
  ps.zB = 2048L * 1024; ps.ldb = 1024;
  ps.Cf = S; ps.zC = 2048L * 2048; ps.ldc = 2048; ps.scale = 0.03125f;
  gemmdp<256><<<dim3(8, 8, 4), 512, 0, stream>>>(ps);

  softmax_rows<<<8192, 256, 0, stream>>>(S);

  // --- attn = P @ V -> out[:, :, 1024:], BN=128 -> 256 blocks ---
  G8 po = {};
  const _Float16* P = (const _Float16*)S;  // rows stride 4096 f16
  po.Areg[0] = P; po.Areg[1] = P + 1024; po.Areg[2] = P;
  po.zA = 2048L * 4096; po.lda = 4096;
  for (int zz = 0; zz < 4; ++zz) {
    po.Breg[zz][0] = VT; po.Breg[zz][1] = VT + 1024; po.Breg[zz][2] = VT;
    po.NT[zz] = 32; po.emode[zz] = EM_F32;
  }
  po.zB = 1024L * 2048; po.ldb = 2048;
  po.Cf = out + 1024; po.zC = 2048L * 2048; po.ldc = 2048; po.scale = 1.f;
  gemmdp<128><<<dim3(8, 8, 4), 512, 0, stream>>>(po);
}

// Round 6
// 338.037 us; speedup vs baseline: 1.1690x; 1.1675x over previous
//
#include <hip/hip_runtime.h>
#include <stdint.h>

// ============================================================================
// AttentionBlock: out = concat([x, softmax(QK^T/32) @ V], -1)
//   B=4, S=2048, D=1024, fp32 in/out.
//
// fp32 emulated via f16 hi/lo split on the Q/K/logits path, folded into the
// K dimension: A''=[Ah|Al|Ah], B''=[Bh|Bh|Bl], K=3072 -> plain f16 GEMMs
// with a per-K-region source table.
//
// GEMM template (BMxBN tile, BK=64, 8 waves 2Mx4N, dbuf LDS, gload_lds +
// T2 pre-swizzled source, T1 XCD swizzle): 4 phases/K-tile, fragment reuse
// (Gray order), 24 ds_read_b128/wave/tile at BM=BN=256:
//   P0: read A-quad0+B-half0; stage B0(t+1); BAR; lgkm0; MFMA A0xB0; W0; BAR
//   P1: read B-half1;         stage B1(t+1); BAR; lgkm0; MFMA A0xB1; W1; BAR
//   P2: read A-quad1;         stage A1(t+1); BAR; lgkm0; MFMA A1xB1;     BAR
//   P3: (no reads);           stage A0(t+2);                MFMA A1xB0; W3; BAR
// Ledger (loads/unit/thread: LA=BM/128, LB=BN/128), derived and verified
// against the two r5-passing configs (256x256: 6,6,6,6,4,2 / 256x128:
// 5,5,4,5,3,2):  PRO=W0=W3=2LA+LB, W1=LA+2LB, W3b=LA+LB, W0c=LA.
// Staging leads 3-4 phases; never drains to 0 in main loop (T4).
// A0(t+2) targets the CURRENT read-buf's A0 region — safe: all waves' A0
// reads completed before P0's end barrier (3 barriers earlier).
//
// ROUND-6 FIX (counter-driven): the old 384-block proj launch with 128KiB
// LDS/block = 1 block/CU ran as TWO serialized machine rounds (196us, top
// dispatch). Now: projQK = 256 blocks exactly (one balanced round), projV =
// separate 256-block launch with BM=128.
//
// ws layout (144 MiB):
//    0 MB Qh | 16 Ql | 32 Kh | 48 Kl | 64 VT f16 [4][1024][2048]
//   80 MB S f32 [4][2048][2048] (P f16 written in-place, row stride 8192B)
//   overlay on S (dead before S written): 80 xh | 96 xl | 112.. W*T hi/lo
// ============================================================================

typedef _Float16 h8 __attribute__((ext_vector_type(8)));
typedef _Float16 h4 __attribute__((ext_vector_type(4)));
typedef float    f4 __attribute__((ext_vector_type(4)));

#define BAR() __builtin_amdgcn_s_barrier()
#define LGKM0_FENCE()                                      \
  asm volatile("s_waitcnt lgkmcnt(0)" ::: "memory");       \
  __builtin_amdgcn_sched_barrier(0)

template <int N>
__device__ __forceinline__ void vmw() {
  if constexpr (N == 0) asm volatile("s_waitcnt vmcnt(0)" ::: "memory");
  else if constexpr (N == 1) asm volatile("s_waitcnt vmcnt(1)" ::: "memory");
  else if constexpr (N == 2) asm volatile("s_waitcnt vmcnt(2)" ::: "memory");
  else if constexpr (N == 3) asm volatile("s_waitcnt vmcnt(3)" ::: "memory");
  else if constexpr (N == 4) asm volatile("s_waitcnt vmcnt(4)" ::: "memory");
  else if constexpr (N == 5) asm volatile("s_waitcnt vmcnt(5)" ::: "memory");
  else if constexpr (N == 6) asm volatile("s_waitcnt vmcnt(6)" ::: "memory");
}

__device__ __forceinline__ void gl_lds16(const _Float16* g, _Float16* l) {
  __builtin_amdgcn_global_load_lds(
      (const __attribute__((address_space(1))) unsigned int*)g,
      (__attribute__((address_space(3))) unsigned int*)l, 16, 0, 0);
}

// ---------------------------------------------------------------- prep ----
__global__ __launch_bounds__(256) void prep_x_split_copy(
    const float* __restrict__ x, _Float16* __restrict__ xh,
    _Float16* __restrict__ xl, float* __restrict__ out) {
  size_t i = (size_t)blockIdx.x * 256 + threadIdx.x;  // one f4 per thread
  f4 v = ((const f4*)x)[i];
  h4 hi, lo;
#pragma unroll
  for (int j = 0; j < 4; ++j) {
    _Float16 h = (_Float16)v[j];
    hi[j] = h;
    lo[j] = (_Float16)(v[j] - (float)h);
  }
  ((h4*)xh)[i] = hi;
  ((h4*)xl)[i] = lo;
  size_t r = i >> 8, c = i & 255;       // out[:, :1024] = x (fused copy)
  ((f4*)out)[r * 512 + c] = v;
}

__global__ __launch_bounds__(256) void prep_w_split(const float* __restrict__ W,
                                                    _Float16* __restrict__ WTh,
                                                    _Float16* __restrict__ WTl) {
  int i = blockIdx.x * 256 + threadIdx.x;
  int d = i >> 10, e = i & 1023;
  float v = W[i];
  _Float16 h = (_Float16)v;
  WTh[e * 1024 + d] = h;
  if (WTl) WTl[e * 1024 + d] = (_Float16)(v - (float)h);
}

// ---------------------------------------------------------------- gemm ----
enum { EM_F32 = 0, EM_QK = 1, EM_VT = 2 };

struct G8 {
  const _Float16* Areg[3]; long zA; int lda;     // A region table (k0>>10)
  const _Float16* Breg[4][3]; long zB; int ldb;  // B region table per z
  int NT[4];     // K-tiles (K/64) per z
  int emode[4];  // epilogue per z
  float* Cf; long zC; int ldc; float scale;      // EM_F32
  _Float16* Ch[4]; _Float16* Cl[4];              // EM_QK (ld = 1024)
  _Float16* Vt;                                  // EM_VT: [b][1024][2048]
};

template <int BM, int BN>
__global__ __launch_bounds__(512, 2) void gemmdp(G8 p) {
  constexpr int MFR = BM / 32;   // m-frags per wave (8 or 4)
  constexpr int MPH = MFR / 2;   // m-frags per A-quad
  constexpr int NFR = BN / 64;   // n-frags per wave (4 or 2)
  constexpr int NPH = NFR / 2;   // n-frags per B-half
  constexpr int LA = BM / 128;   // gl_lds loads per A-unit per thread
  constexpr int LB = BN / 128;
  __shared__ alignas(16) _Float16 ldsA[2][BM][64];
  __shared__ alignas(16) _Float16 ldsB[2][BN][64];

  const int t0 = threadIdx.x;
  const int lane = t0 & 63;
  const int w = t0 >> 6;
  const int wm = w >> 2, wn = w & 3;           // wave grid 2(M) x 4(N)
  const int l15 = lane & 15, l4 = lane >> 4;

  // T1: bijective XCD-aware block swizzle (nwg % 8 == 0 for all launches)
  const int nbx = gridDim.x, nby = gridDim.y;
  const int nwg = nbx * nby * gridDim.z;
  const int bid = blockIdx.x + nbx * (blockIdx.y + nby * blockIdx.z);
  const int nb = (bid & 7) * (nwg >> 3) + (bid >> 3);
  const int bx = nb % nbx, by = (nb / nbx) % nby, z = nb / (nbx * nby);

  const long Mb = (long)by * BM;
  const long Nb = (long)bx * BN;
  const int nt = p.NT[z];
  const long zAo = p.zA * z;
  const long zBo = p.zB * z;
  const int lda = p.lda, ldb = p.ldb;

  const int rr_lo = t0 >> 3;            // staging: 8 lanes per 64-f16 row
  const int slot = t0 & 7;
  const int rr0_lo = (t0 & ~63) >> 3;   // wave-uniform row part

  f4 acc[MFR][NFR] = {};                // wave tile (BM/2) x (16*NFR)

  // stage unit u (0:A-quad0, 1:B-half0, 2:B-half1, 3:A-quad1) of kt -> buf sb
  auto stageU = [&](int u, int sb, int kt) {
    const int k0 = kt << 6;
    const int r = k0 >> 10;
    const int cn = k0 & 1023;
    if (u == 0 || u == 3) {
      const _Float16* Ab = p.Areg[r] + zAo + cn;
      const int qm = (u == 3);
      constexpr int QS = BM / 4;
#pragma unroll
      for (int i = 0; i < LA; ++i) {
        int rr = i * 64 + rr_lo;
        int rr0 = i * 64 + rr0_lo;
        int row  = (rr  / QS) * (BM / 2) + qm * QS + (rr  % QS);
        int row0 = (rr0 / QS) * (BM / 2) + qm * QS + (rr0 % QS);
        int scol = (slot ^ (row & 7)) << 3;     // pre-swizzled source (T2)
        gl_lds16(Ab + (Mb + row) * (long)lda + scol, &ldsA[sb][row0][0]);
      }
    } else {
      const _Float16* Bb = p.Breg[z][r] + zBo + cn;
      const int hh = (u == 2);
      constexpr int QS = BN / 4;
#pragma unroll
      for (int i = 0; i < LB; ++i) {
        int rr = i * 64 + rr_lo;
        int rr0 = i * 64 + rr0_lo;
        int row  = (rr  / QS) * (BN / 2) + hh * QS + (rr  % QS);
        int row0 = (rr0 / QS) * (BN / 2) + hh * QS + (rr0 % QS);
        int scol = (slot ^ (row & 7)) << 3;
        gl_lds16(Bb + (Nb + row) * (long)ldb + scol, &ldsB[sb][row0][0]);
      }
    }
  };

  h8 af[MPH][2];        // current A-quad (reused across 2 phases)
  h8 bfh[2][NPH][2];    // both B-halves (B0 live P0->P3)

  auto dsA = [&](int qm, int buf) {
#pragma unroll
    for (int m = 0; m < MPH; ++m) {
      int row = wm * (BM / 2) + (qm * MPH + m) * 16 + l15;
#pragma unroll
      for (int ks = 0; ks < 2; ++ks)
        af[m][ks] = *(const h8*)&ldsA[buf][row][(((ks * 4 + l4) ^ (row & 7)) << 3)];
    }
  };
  auto dsB = [&](int hh, int buf) {
#pragma unroll
    for (int n = 0; n < NPH; ++n) {
      int row = wn * (16 * NFR) + (hh * NPH + n) * 16 + l15;
#pragma unroll
      for (int ks = 0; ks < 2; ++ks)
        bfh[hh][n][ks] = *(const h8*)&ldsB[buf][row][(((ks * 4 + l4) ^ (row & 7)) << 3)];
    }
  };
  auto mfmaQ = [&](int qm, int hh) {    // A-quad x B-half x K=64
    __builtin_amdgcn_s_setprio(1);
#pragma unroll
    for (int ks = 0; ks < 2; ++ks)
#pragma unroll
      for (int m = 0; m < MPH; ++m)
#pragma unroll
        for (int n = 0; n < NPH; ++n)
          acc[qm * MPH + m][hh * NPH + n] = __builtin_amdgcn_mfma_f32_16x16x32_f16(
              af[m][ks], bfh[hh][n][ks], acc[qm * MPH + m][hh * NPH + n], 0, 0, 0);
    __builtin_amdgcn_s_setprio(0);
  };

  // in-flight ledger (verified against both r5-passing configs)
  constexpr int PRO = 2 * LA + LB;
  constexpr int W0  = 2 * LA + LB;
  constexpr int W1  = LA + 2 * LB;
  constexpr int W3  = 2 * LA + LB;
  constexpr int W3b = LA + LB;
  constexpr int W0c = LA;

  // prologue: A0(0),B0(0),B1(0),A1(0) -> buf0; A0(1) -> buf1
  stageU(0, 0, 0); stageU(1, 0, 0); stageU(2, 0, 0); stageU(3, 0, 0);
  stageU(0, 1, 1);
  vmw<PRO>();
  BAR();

  int kt = 0;
  for (; kt + 2 < nt; ++kt) {
    const int buf = kt & 1;
    // P0
    dsA(0, buf); dsB(0, buf);
    stageU(1, buf ^ 1, kt + 1);
    BAR(); LGKM0_FENCE();
    mfmaQ(0, 0);
    vmw<W0>(); BAR();
    // P1
    dsB(1, buf);
    stageU(2, buf ^ 1, kt + 1);
    BAR(); LGKM0_FENCE();
    mfmaQ(0, 1);
    vmw<W1>(); BAR();
    // P2
    dsA(1, buf);
    stageU(3, buf ^ 1, kt + 1);
    BAR(); LGKM0_FENCE();
    mfmaQ(1, 1);
    BAR();
    // P3 (no reads; A0(kt+2) -> CURRENT buf A0 region, read-dead since P0)
    stageU(0, buf, kt + 2);
    mfmaQ(1, 0);
    vmw<W3>(); BAR();
  }
  {  // kt = nt-2: stage B0,B1,A1(nt-1) only
    const int buf = kt & 1;
    dsA(0, buf); dsB(0, buf);
    stageU(1, buf ^ 1, kt + 1);
    BAR(); LGKM0_FENCE();
    mfmaQ(0, 0);
    vmw<W0>(); BAR();
    dsB(1, buf);
    stageU(2, buf ^ 1, kt + 1);
    BAR(); LGKM0_FENCE();
    mfmaQ(0, 1);
    vmw<W1>(); BAR();
    dsA(1, buf);
    stageU(3, buf ^ 1, kt + 1);
    BAR(); LGKM0_FENCE();
    mfmaQ(1, 1);
    BAR();
    mfmaQ(1, 0);
    vmw<W3b>(); BAR();
    ++kt;
  }
  {  // kt = nt-1: no staging; drain
    const int buf = kt & 1;
    dsA(0, buf); dsB(0, buf);
    BAR(); LGKM0_FENCE();
    mfmaQ(0, 0);
    vmw<W0c>(); BAR();
    dsB(1, buf);
    BAR(); LGKM0_FENCE();
    mfmaQ(0, 1);
    vmw<0>(); BAR();
    dsA(1, buf);
    BAR(); LGKM0_FENCE();
    mfmaQ(1, 1);
    mfmaQ(1, 0);          // epilogue is LDS-free
  }

  // epilogue: C/D map col=lane&15, row=(lane>>4)*4+reg (verified r1/r3/r5)
  const int em = p.emode[z];
  const long gr0 = wm * (BM / 2) + l4 * 4;
  const long gc0 = wn * (16 * NFR) + l15;
  if (em == EM_F32) {
    float* C = p.Cf + p.zC * z;
#pragma unroll
    for (int i = 0; i < MFR; ++i)
#pragma unroll
      for (int j = 0; j < NFR; ++j) {
        long gr = Mb + gr0 + i * 16;
        long gc = Nb + gc0 + j * 16;
#pragma unroll
        for (int r = 0; r < 4; ++r)
          C[(gr + r) * (long)p.ldc + gc] = acc[i][j][r] * p.scale;
      }
  } else if (em == EM_QK) {
    _Float16* Ch = p.Ch[z];
    _Float16* Cl = p.Cl[z];
#pragma unroll
    for (int i = 0; i < MFR; ++i)
#pragma unroll
      for (int j = 0; j < NFR; ++j) {
        long gr = Mb + gr0 + i * 16;
        long gc = Nb + gc0 + j * 16;
#pragma unroll
        for (int r = 0; r < 4; ++r) {
          float c = acc[i][j][r];
          _Float16 h = (_Float16)c;
          Ch[(gr + r) * 1024 + gc] = h;
          Cl[(gr + r) * 1024 + gc] = (_Float16)(c - (float)h);
        }
      }
  } else {  // EM_VT: rows = b*2048+s, col = d -> Vt[b][d][s], 4 contiguous s
    _Float16* Vt = p.Vt;
#pragma unroll
    for (int i = 0; i < MFR; ++i)
#pragma unroll
      for (int j = 0; j < NFR; ++j) {
        long gr = Mb + gr0 + i * 16;
        long gc = Nb + gc0 + j * 16;
        long b = gr >> 11, s = gr & 2047;
        h4 hv;
#pragma unroll
        for (int r = 0; r < 4; ++r) hv[r] = (_Float16)acc[i][j][r];
        *(h4*)&Vt[b * (long)(1024 * 2048) + gc * 2048 + s] = hv;
      }
  }
}

// ------------------------------------------------------------- softmax ----
__global__ __launch_bounds__(256) void softmax_rows(float* __restrict__ Sb) {
  const int t = threadIdx.x;
  float* row = Sb + (size_t)blockIdx.x * 2048;
  f4 v0 = ((const f4*)row)[t];
  f4 v1 = ((const f4*)row)[t + 256];
  float mx = -3.0e38f;
#pragma unroll
  for (int j = 0; j < 4; ++j) { mx = fmaxf(mx, v0[j]); mx = fmaxf(mx, v1[j]); }
#pragma unroll
  for (int o = 32; o > 0; o >>= 1) mx = fmaxf(mx, __shfl_xor(mx, o));
  __shared__ float red[4], red2[4];
  const int wave = t >> 6, lane = t & 63;
  if (lane == 0) red[wave] = mx;
  __syncthreads();
  mx = fmaxf(fmaxf(red[0], red[1]), fmaxf(red[2], red[3]));
  float pv[8];
  float sum = 0.f;
#pragma unroll
  for (int j = 0; j < 4; ++j) { pv[j] = __expf(v0[j] - mx); pv[4 + j] = __expf(v1[j] - mx); }
#pragma unroll
  for (int j = 0; j < 8; ++j) sum += pv[j];
#pragma unroll
  for (int o = 32; o > 0; o >>= 1) sum += __shfl_xor(sum, o);
  if (lane == 0) red2[wave] = sum;
  __syncthreads();  // orders all row reads before in-place f16 writes
  sum = red2[0] + red2[1] + red2[2] + red2[3];
  float inv = 1.0f / sum;
  h4 o0, o1;
#pragma unroll
  for (int j = 0; j < 4; ++j) { o0[j] = (_Float16)(pv[j] * inv); o1[j] = (_Float16)(pv[4 + j] * inv); }
  _Float16* prow = (_Float16*)row;
  ((h4*)prow)[t] = o0;
  ((h4*)prow)[t + 256] = o1;
}

// ---------------------------------------------------------------- misc ----
__global__ __launch_bounds__(256) void copy_x_half(const float* __restrict__ x,
                                                   float* __restrict__ out) {
  size_t i = (size_t)blockIdx.x * 256 + threadIdx.x;
  size_t r = i >> 8, c = i & 255;
  ((f4*)out)[r * 512 + c] = ((const f4*)x)[i];
}

__global__ void ws_sentinel(float* out, float v) { out[0] = v; }

// -------------------------------------------------------------- launch ----
extern "C" void kernel_launch(void* const* d_in, const int* in_sizes, int n_in,
                              void* d_out, int out_size, void* d_ws, size_t ws_size,
                              hipStream_t stream) {
  const float* x  = (const float*)d_in[0];
  const float* Wq = (const float*)d_in[1];
  const float* Wk = (const float*)d_in[2];
  const float* Wv = (const float*)d_in[3];
  float* out = (float*)d_out;

  const size_t MB = 1ull << 20;
  char* w = (char*)d_ws;
  _Float16* Qh = (_Float16*)(w + 0 * MB);
  _Float16* Ql = (_Float16*)(w + 16 * MB);
  _Float16* Kh = (_Float16*)(w + 32 * MB);
  _Float16* Kl = (_Float16*)(w + 48 * MB);
  _Float16* VT = (_Float16*)(w + 64 * MB);
  float*    S  = (float*)   (w + 80 * MB);
  _Float16* xh = (_Float16*)(w + 80 * MB);  // overlays S (dead before S write)
  _Float16* xl = (_Float16*)(w + 96 * MB);
  _Float16* WqhT = (_Float16*)(w + 112 * MB);
  _Float16* WqlT = (_Float16*)(w + 114 * MB);
  _Float16* WkhT = (_Float16*)(w + 116 * MB);
  _Float16* WklT = (_Float16*)(w + 118 * MB);
  _Float16* WvhT = (_Float16*)(w + 120 * MB);

  if (ws_size < 144 * MB) {  // fail loud: absmax reports ~ws_size
    copy_x_half<<<8192, 256, 0, stream>>>(x, out);
    ws_sentinel<<<1, 1, 0, stream>>>(out, (float)ws_size);
    return;
  }

  prep_x_split_copy<<<8192, 256, 0, stream>>>(x, xh, xl, out);
  prep_w_split<<<4096, 256, 0, stream>>>(Wq, WqhT, WqlT);
  prep_w_split<<<4096, 256, 0, stream>>>(Wk, WkhT, WklT);
  prep_w_split<<<4096, 256, 0, stream>>>(Wv, WvhT, (_Float16*)nullptr);

  // --- Q,K (split, K=3072): 256 blocks = one balanced machine round ---
  G8 pp = {};
  pp.Areg[0] = xh; pp.Areg[1] = xl; pp.Areg[2] = xh; pp.zA = 0; pp.lda = 1024;
  pp.Breg[0][0] = WqhT; pp.Breg[0][1] = WqhT; pp.Breg[0][2] = WqlT;
  pp.Breg[1][0] = WkhT; pp.Breg[1][1] = WkhT; pp.Breg[1][2] = WklT;
  pp.zB = 0; pp.ldb = 1024;
  pp.NT[0] = 48; pp.NT[1] = 48;
  pp.emode[0] = EM_QK; pp.emode[1] = EM_QK;
  pp.Ch[0] = Qh; pp.Cl[0] = Ql; pp.Ch[1] = Kh; pp.Cl[1] = Kl;
  gemmdp<256, 256><<<dim3(4, 32, 2), 512, 0, stream>>>(pp);

  // --- V = x @ Wv (plain, K=1024): BM=128 -> 256 blocks, stored VT ---
  G8 pv = {};
  pv.Areg[0] = xh; pv.Areg[1] = xh; pv.Areg[2] = xh; pv.zA = 0; pv.lda = 1024;
  pv.Breg[0][0] = WvhT; pv.Breg[0][1] = WvhT; pv.Breg[0][2] = WvhT;
  pv.zB = 0; pv.ldb = 1024;
  pv.NT[0] = 16; pv.emode[0] = EM_VT;
  pv.Vt = VT;
  gemmdp<128, 256><<<dim3(4, 64, 1), 512, 0, stream>>>(pv);

  // --- S = (Q K^T)/32, split K=3072, 256 blocks ---
  G8 ps = {};
  ps.Areg[0] = Qh; ps.Areg[1] = Ql; ps.Areg[2] = Qh;
  ps.zA = 2048L * 1024; ps.lda = 1024;
  for (int zz = 0; zz < 4; ++zz) {
    ps.Breg[zz][0] = Kh; ps.Breg[zz][1] = Kh; ps.Breg[zz][2] = Kl;
    ps.NT[zz] = 48; ps.emode[zz] = EM_F32;
  }
  ps.zB = 2048L * 1024; ps.ldb = 1024;
  ps.Cf = S; ps.zC = 2048L * 2048; ps.ldc = 2048; ps.scale = 0.03125f;
  gemmdp<256, 256><<<dim3(8, 8, 4), 512, 0, stream>>>(ps);

  softmax_rows<<<8192, 256, 0, stream>>>(S);

  // --- attn = P @ V -> out[:, :, 1024:], BN=128 -> 256 blocks ---
  G8 po = {};
  const _Float16* P = (const _Float16*)S;  // rows stride 4096 f16
  po.Areg[0] = P; po.Areg[1] = P + 1024; po.Areg[2] = P;
  po.zA = 2048L * 4096; po.lda = 4096;
  for (int zz = 0; zz < 4; ++zz) {
    po.Breg[zz][0] = VT; po.Breg[zz][1] = VT + 1024; po.Breg[zz][2] = VT;
    po.NT[zz] = 32; po.emode[zz] = EM_F32;
  }
  po.zB = 1024L * 2048; po.ldb = 2048;
  po.Cf = out + 1024; po.zC = 2048L * 2048; po.ldc = 2048; po.scale = 1.f;
  gemmdp<256, 128><<<dim3(8, 8, 4), 512, 0, stream>>>(po);
}